// Round 3
// baseline (1347.103 us; speedup 1.0000x reference)
//
#include <hip/hip_runtime.h>
#include <hip/hip_bf16.h>

// 2-layer 4-direction MDLSTM, fused single kernel. B=256, Wd=2048, OUT=11.
// One block per batch b (256 threads). Wave 0 runs BOTH serial scans with
// lane = d*16 + j: each lane owns unit j of direction d and computes all 4
// live gates (i, f_w, o, a; f_h is dead) as two float2 packed dots
// (v_pk_fma_f32). h-broadcast = 11 ds_bpermute within the 16-lane group
// (no readlanes, no cross-class gather). Inactive lanes (j>=11) ds_add into
// a pad region -> branch-free store. Waves 1-3 only help in parallel phases
// (height-sum, y1->bf16 convert, zeroing, writeout).
//
// LDS: acc (88KB fp32, dir-sum accumulator, reused by both layers) +
//      ybuf (44KB: xw fp32 strip during L1, y1 bf16 strip during L2) = 132KB.
// No global workspace, no memsets, 1 dispatch.

#define NOUT 11
#define WD 2048
#define NB 256
#define Y1N (WD * NOUT)  // 22528

typedef float f2 __attribute__((ext_vector_type(2)));

__device__ __forceinline__ float bperm(int byteidx, float v) {
  return __int_as_float(__builtin_amdgcn_ds_bpermute(byteidx, __float_as_int(v)));
}
__device__ __forceinline__ f2 fma2(float s, f2 w, f2 a) {
  f2 sv = {s, s};
  return __builtin_elementwise_fma(sv, w, a);
}
__device__ __forceinline__ float sigm(float x) {
  return __builtin_amdgcn_rcpf(1.0f + __expf(-x));
}
__device__ __forceinline__ float tanh_(float x) {
  return fmaf(2.0f, __builtin_amdgcn_rcpf(1.0f + __expf(-2.0f * x)), -1.0f);
}

__global__ __launch_bounds__(256, 1) void mdlstm_fused(
    const float* __restrict__ x, const float* __restrict__ W0,
    const float* __restrict__ U0, const float* __restrict__ b0,
    const float* __restrict__ W1, const float* __restrict__ U1,
    const float* __restrict__ b1, float* __restrict__ out) {
  __shared__ float acc[Y1N + 64];                 // 88 KB + pad (dummy slots)
  __shared__ __align__(16) char ybuf[Y1N * 2];    // 44 KB (xw | y1-bf16)

  const int tid = threadIdx.x;
  const int b = blockIdx.x;
  float* xw = (float*)ybuf;                       // 8 KB live during L1
  __hip_bfloat16* ylds = (__hip_bfloat16*)ybuf;   // 44 KB live during L2

  // ---- Phase A: height-sum x -> xw; zero acc ----
  const float* xb = x + (size_t)b * 32 * WD;
  for (int w = tid; w < WD; w += 256) {
    float s = 0.f;
#pragma unroll
    for (int h = 0; h < 32; ++h) s += xb[h * WD + w];
    xw[w] = s;
  }
  for (int i = tid; i < Y1N + 64; i += 256) acc[i] = 0.f;
  __syncthreads();

  // ---- Phase B: layer-1 scan (wave 0 only) ----
  if (tid < 64) {
    const int lane = tid;
    const int d = lane >> 4;
    const int j = lane & 15;
    const int jc = (j < NOUT) ? j : (NOUT - 1);
    const bool act_lane = (j < NOUT);
    const bool fwd = ((d & 1) == 0);
    const int grp = lane & 48;
    int pidx[NOUT];
#pragma unroll
    for (int s = 0; s < NOUT; ++s) pidx[s] = (grp + s) << 2;
    const int ic = jc, fc = 11 + jc, oc = 33 + jc, ac = 44 + jc;

    {  // ---------- layer 1 ----------
      f2 U2A[NOUT], U2B[NOUT];
#pragma unroll
      for (int s = 0; s < NOUT; ++s) {
        const float* Up = U0 + (d * NOUT + s) * 55;
        U2A[s] = (f2){Up[ic], Up[fc]};
        U2B[s] = (f2){Up[oc], Up[ac]};
      }
      const float* Wp = W0 + d * 55;
      const f2 w2A = {Wp[ic], Wp[fc]}, w2B = {Wp[oc], Wp[ac]};
      const float* bp = b0 + d * 55;
      const f2 b2A = {bp[ic], bp[fc]}, b2B = {bp[oc], bp[ac]};

      int xo = fwd ? 0 : (WD - 1);
      const int xdl = fwd ? 1 : -1;
      int ao = act_lane ? (fwd ? jc : ((WD - 1) * NOUT + jc)) : (Y1N + lane);
      const int adl = act_lane ? (fwd ? NOUT : -NOUT) : 0;

      float hj = 0.f, cj = 0.f;
      // input stage for t=0
      float xv0 = xw[xo];
      xo += xdl;
      f2 giA = {fmaf(xv0, w2A.x, b2A.x), fmaf(xv0, w2A.y, b2A.y)};
      f2 giB = {fmaf(xv0, w2B.x, b2B.x), fmaf(xv0, w2B.y, b2B.y)};

      for (int t = 0; t < WD; ++t) {
        // chain head: broadcast h within direction group
        float hs[NOUT];
#pragma unroll
        for (int s = 0; s < NOUT; ++s) hs[s] = bperm(pidx[s], hj);
        // next input read (off-chain, clamped at the tail)
        const float xvn = xw[xo & (WD - 1)];
        xo += xdl;
        // recurrent dot
        f2 gA = giA, gB = giB;
#pragma unroll
        for (int s = 0; s < NOUT; ++s) {
          gA = fma2(hs[s], U2A[s], gA);
          gB = fma2(hs[s], U2B[s], gB);
        }
        // activations + state update
        const float iv = sigm(gA.x), fv = sigm(gA.y);
        const float ov = sigm(gB.x), av = tanh_(gB.y);
        cj = fmaf(fv, cj, iv * av);
        hj = ov * tanh_(cj);
        atomicAdd(&acc[ao], hj);
        ao += adl;
        // next input stage (off-chain)
        giA = (f2){fmaf(xvn, w2A.x, b2A.x), fmaf(xvn, w2A.y, b2A.y)};
        giB = (f2){fmaf(xvn, w2B.x, b2B.x), fmaf(xvn, w2B.y, b2B.y)};
      }
    }
  }
  __syncthreads();

  // ---- Phase C: acc (y1 fp32) -> ylds (bf16); re-zero acc ----
  for (int i = tid; i < Y1N; i += 256) ylds[i] = __float2bfloat16(acc[i]);
  __syncthreads();
  for (int i = tid; i < Y1N + 64; i += 256) acc[i] = 0.f;
  __syncthreads();

  // ---- Phase D: layer-2 scan (wave 0 only) ----
  if (tid < 64) {
    const int lane = tid;
    const int d = lane >> 4;
    const int j = lane & 15;
    const int jc = (j < NOUT) ? j : (NOUT - 1);
    const bool act_lane = (j < NOUT);
    const bool fwd = ((d & 1) == 0);
    const int grp = lane & 48;
    int pidx[NOUT];
#pragma unroll
    for (int s = 0; s < NOUT; ++s) pidx[s] = (grp + s) << 2;
    const int ic = jc, fc = 11 + jc, oc = 33 + jc, ac = 44 + jc;

    {  // ---------- layer 2 ----------
      f2 U2A[NOUT], U2B[NOUT], W2A[NOUT], W2B[NOUT];
#pragma unroll
      for (int s = 0; s < NOUT; ++s) {
        const float* Up = U1 + (d * NOUT + s) * 55;
        U2A[s] = (f2){Up[ic], Up[fc]};
        U2B[s] = (f2){Up[oc], Up[ac]};
        const float* Wp = W1 + (d * NOUT + s) * 55;
        W2A[s] = (f2){Wp[ic], Wp[fc]};
        W2B[s] = (f2){Wp[oc], Wp[ac]};
      }
      const float* bp = b1 + d * 55;
      const f2 b2A = {bp[ic], bp[fc]}, b2B = {bp[oc], bp[ac]};

      int yo = fwd ? jc : ((WD - 1) * NOUT + jc);
      const int ydl = fwd ? NOUT : -NOUT;
      int ao = act_lane ? (fwd ? jc : ((WD - 1) * NOUT + jc)) : (Y1N + lane);
      const int adl = act_lane ? (fwd ? NOUT : -NOUT) : 0;

      float hj = 0.f, cj = 0.f;
      f2 giA, giB;
      {  // input stage for t=0
        const float yv = __bfloat162float(ylds[yo]);
        yo += ydl;
        float ys[NOUT];
#pragma unroll
        for (int s = 0; s < NOUT; ++s) ys[s] = bperm(pidx[s], yv);
        giA = b2A;
        giB = b2B;
#pragma unroll
        for (int s = 0; s < NOUT; ++s) {
          giA = fma2(ys[s], W2A[s], giA);
          giB = fma2(ys[s], W2B[s], giB);
        }
      }

      for (int t = 0; t < WD; ++t) {
        // chain head: broadcast h
        float hs[NOUT];
#pragma unroll
        for (int s = 0; s < NOUT; ++s) hs[s] = bperm(pidx[s], hj);
        // next input element read early (off-chain; clamp at tail)
        const int yor = ((unsigned)yo < (unsigned)Y1N) ? yo : 0;
        const float yvn = __bfloat162float(ylds[yor]);
        yo += ydl;
        // recurrent dot
        f2 gA = giA, gB = giB;
#pragma unroll
        for (int s = 0; s < NOUT; ++s) {
          gA = fma2(hs[s], U2A[s], gA);
          gB = fma2(hs[s], U2B[s], gB);
        }
        // activations + state update
        const float iv = sigm(gA.x), fv = sigm(gA.y);
        const float ov = sigm(gB.x), av = tanh_(gB.y);
        cj = fmaf(fv, cj, iv * av);
        hj = ov * tanh_(cj);
        atomicAdd(&acc[ao], hj);
        ao += adl;
        // next input stage (off-chain)
        float ys[NOUT];
#pragma unroll
        for (int s = 0; s < NOUT; ++s) ys[s] = bperm(pidx[s], yvn);
        giA = b2A;
        giB = b2B;
#pragma unroll
        for (int s = 0; s < NOUT; ++s) {
          giA = fma2(ys[s], W2A[s], giA);
          giB = fma2(ys[s], W2B[s], giB);
        }
      }
    }
  }
  __syncthreads();

  // ---- Phase E: transposed writeout out[b][j][w] = acc[w*11+j] ----
  float* ob = out + (size_t)b * Y1N;
  for (int i = tid; i < Y1N; i += 256) {
    const int jj = i >> 11;       // i / WD
    const int w = i & (WD - 1);   // i % WD
    ob[i] = acc[w * NOUT + jj];
  }
}

extern "C" void kernel_launch(void* const* d_in, const int* in_sizes, int n_in,
                              void* d_out, int out_size, void* d_ws,
                              size_t ws_size, hipStream_t stream) {
  const float* x  = (const float*)d_in[0];
  const float* W0 = (const float*)d_in[1];
  const float* U0 = (const float*)d_in[2];
  const float* b0 = (const float*)d_in[3];
  const float* W1 = (const float*)d_in[4];
  const float* U1 = (const float*)d_in[5];
  const float* b1 = (const float*)d_in[6];
  float* out = (float*)d_out;

  mdlstm_fused<<<NB, 256, 0, stream>>>(x, W0, U0, b0, W1, U1, b1, out);
}